// Round 1
// baseline (328.839 us; speedup 1.0000x reference)
//
#include <hip/hip_runtime.h>
#include <hip/hip_bf16.h>

// PointPillarScatter: scatter V=40000 pillars (64ch fp32) to 512x512 canvas,
// 1x1 conv (64x64) + bias, broadcast to B=4.  Output (4,64,512,512) fp32.
//
// Strategy: inverse map + per-pillar conv results, then a single coalesced
// write pass over the whole output (no fill-then-overwrite double traffic).

#define V_PILLARS 40000
#define XDIM 512
#define YDIM 512
#define C 64          // IN_C == OUT_C == 64
#define BATCH 4

// ---------------- K1: per-pillar conv + inverse-map scatter -----------------
// grid: 1024 blocks x 256 threads. Each wave (64 lanes, lane==o) processes
// pillars p = global_wave, stride n_waves. conv_w row o lives in 16 float4
// registers (staged through LDS once to avoid a 64-cache-line gather).
__global__ __launch_bounds__(256) void k_pillar_conv(
    const float* __restrict__ pf,     // (V,64)
    const float* __restrict__ cw,     // (64,64) row-major [o][c]
    const float* __restrict__ cb,     // (64,)
    const int*   __restrict__ vidx,   // (V,2)
    int*   __restrict__ map,          // (512*512) pre-set to -1
    float* __restrict__ res)          // (V,64)
{
    __shared__ float swt[64 * 68];    // conv_w, rows padded to 68 floats
    const int t    = threadIdx.x;
    const int lane = t & 63;
    const int w    = t >> 6;

    // cooperative coalesced load of conv_w (16 KB) into LDS, padded rows
    for (int i = t; i < 64 * 16; i += 256) {
        const int o = i >> 4, j = i & 15;
        float4 v = ((const float4*)cw)[i];          // i == o*16 + j
        *((float4*)&swt[o * 68 + 4 * j]) = v;
    }
    __syncthreads();

    // each lane pulls its row (one-time 8-way-conflict LDS reads, amortized)
    float4 wr[16];
#pragma unroll
    for (int j = 0; j < 16; j++)
        wr[j] = *((const float4*)&swt[lane * 68 + 4 * j]);
    const float bias = cb[lane];

    const int gw = blockIdx.x * 4 + w;
    const int nw = gridDim.x * 4;
    for (int p = gw; p < V_PILLARS; p += nw) {
        // wave-broadcast loads of this pillar's 64 features (same addr/lane)
        const float4* a4 = (const float4*)(pf + (size_t)p * C);
        float acc = bias;
#pragma unroll
        for (int j = 0; j < 16; j++) {
            const float4 a = a4[j];
            acc += a.x * wr[j].x + a.y * wr[j].y + a.z * wr[j].z + a.w * wr[j].w;
        }
        res[(size_t)p * C + lane] = acc;            // coalesced 256 B
        if (lane == 0) {
            const int xx = vidx[2 * p], yy = vidx[2 * p + 1];
            if (xx >= 0 && xx < XDIM && yy >= 0 && yy < YDIM)
                map[xx * YDIM + yy] = p;
        }
    }
}

// ---------------- K2: single-pass output writer -----------------------------
// grid: 4096 blocks (x in 0..511, y-chunk in 0..7) x 256 threads.
// Stage 64 positions' output rows (res row or bias) into sres[64][65]
// (pad 65 -> 2-way bank aliasing, free), then fully-coalesced dword stores
// to all 64 o-planes x 4 batches.
__global__ __launch_bounds__(256) void k_write_out(
    const float* __restrict__ res,    // (V,64)
    const float* __restrict__ cb,     // (64,)
    const int*   __restrict__ map,    // (512*512)
    float*       __restrict__ out)    // (4,64,512,512)
{
    __shared__ int   smap[64];
    __shared__ float sres[64][65];
    const int t    = threadIdx.x;
    const int lane = t & 63;
    const int w    = t >> 6;
    const int x  = (int)blockIdx.x >> 3;
    const int y0 = ((int)blockIdx.x & 7) << 6;

    if (t < 64) smap[t] = map[x * YDIM + y0 + t];
    const float bias = cb[lane];
    __syncthreads();

    // stage: wave w fills y = w*16 .. w*16+15 (v is wave-uniform -> uniform branch)
#pragma unroll
    for (int i = 0; i < 16; i++) {
        const int y = w * 16 + i;
        const int v = smap[y];
        float val;
        if (v >= 0) val = res[(size_t)v * C + lane];   // coalesced 256 B row
        else        val = bias;
        sres[y][lane] = val;
    }
    __syncthreads();

    // write: wave w handles o = w*16 .. w*16+15; lane == y offset (coalesced)
    const size_t base = (size_t)x * YDIM + y0 + lane;
#pragma unroll
    for (int i = 0; i < 16; i++) {
        const int o = w * 16 + i;
        const float val = sres[lane][o];               // 2-way bank alias, free
        const size_t idx = (size_t)o * (XDIM * YDIM) + base;
        out[idx]                           = val;
        out[idx + 1u * C * XDIM * YDIM]    = val;
        out[idx + 2u * (size_t)C * XDIM * YDIM] = val;
        out[idx + 3u * (size_t)C * XDIM * YDIM] = val;
    }
}

extern "C" void kernel_launch(void* const* d_in, const int* in_sizes, int n_in,
                              void* d_out, int out_size, void* d_ws, size_t ws_size,
                              hipStream_t stream) {
    const float* pf   = (const float*)d_in[0];  // (40000,64)
    const float* cw   = (const float*)d_in[1];  // (64,64)
    const float* cb   = (const float*)d_in[2];  // (64,)
    const int*   vidx = (const int*)d_in[3];    // (40000,2)
    float* out = (float*)d_out;

    // workspace layout: [0,1MB) inverse map, [1MB, 1MB+10.24MB) res
    int*   map = (int*)d_ws;
    float* res = (float*)((char*)d_ws + (1 << 20));

    hipMemsetAsync(map, 0xFF, XDIM * YDIM * sizeof(int), stream);   // map = -1

    k_pillar_conv<<<1024, 256, 0, stream>>>(pf, cw, cb, vidx, map, res);
    k_write_out<<<XDIM * (YDIM / 64), 256, 0, stream>>>(res, cb, map, out);
}